// Round 16
// baseline (459.587 us; speedup 1.0000x reference)
//
#include <hip/hip_runtime.h>
#include <hip/hip_bf16.h>
#include <stdint.h>

typedef __bf16 bf16;
typedef __bf16 bf16x8 __attribute__((ext_vector_type(8)));
typedef __bf16 bf16x4 __attribute__((ext_vector_type(4)));
typedef float  f32x4  __attribute__((ext_vector_type(4)));

#define GLOAD16(gsrc, ldst)                                                        \
  __builtin_amdgcn_global_load_lds(                                               \
      (const __attribute__((address_space(1))) void*)(gsrc),                      \
      (__attribute__((address_space(3))) void*)(ldst), 16, 0, 0)

__device__ __forceinline__ float gelu_f(float v) {
  return 0.5f * v * (1.0f + erff(v * 0.70710678118654752f));
}

// ---- batched transpose+cast for all 8 weights  +  fused ln0 (blocks >= 13824) ----
__global__ __launch_bounds__(256) void transpose_all_k(
    const float* __restrict__ qw0, bf16* __restrict__ qt0,
    const float* __restrict__ pw0, bf16* __restrict__ pt0,
    const float* __restrict__ w10, bf16* __restrict__ t10,
    const float* __restrict__ w20, bf16* __restrict__ t20,
    const float* __restrict__ qw1, bf16* __restrict__ qt1,
    const float* __restrict__ pw1, bf16* __restrict__ pt1,
    const float* __restrict__ w11, bf16* __restrict__ t11,
    const float* __restrict__ w21, bf16* __restrict__ t21,
    const float* __restrict__ x, const float* __restrict__ lng,
    const float* __restrict__ lnb, bf16* __restrict__ lnout) {
  int i = blockIdx.x;
  if (i >= 13824) {
    const int token = (i - 13824) * 4 + (threadIdx.x >> 6);
    const int lane  = threadIdx.x & 63;
    const float4* xp = (const float4*)(x + (size_t)token * 768);
    float4 v[3];
    float s = 0.f, ss = 0.f;
#pragma unroll
    for (int j = 0; j < 3; j++) {
      v[j] = xp[lane + j * 64];
      s  += v[j].x + v[j].y + v[j].z + v[j].w;
      ss += v[j].x * v[j].x + v[j].y * v[j].y + v[j].z * v[j].z + v[j].w * v[j].w;
    }
#pragma unroll
    for (int o = 32; o > 0; o >>= 1) { s += __shfl_xor(s, o); ss += __shfl_xor(ss, o); }
    const float mu  = s * (1.f / 768.f);
    const float var = ss * (1.f / 768.f) - mu * mu;
    const float r   = rsqrtf(var + 1e-5f);
#pragma unroll
    for (int j = 0; j < 3; j++) {
      const int c0 = (lane + j * 64) * 4;
      bf16x4 o4;
      o4[0] = (bf16)((v[j].x - mu) * r * lng[c0 + 0] + lnb[c0 + 0]);
      o4[1] = (bf16)((v[j].y - mu) * r * lng[c0 + 1] + lnb[c0 + 1]);
      o4[2] = (bf16)((v[j].z - mu) * r * lng[c0 + 2] + lnb[c0 + 2]);
      o4[3] = (bf16)((v[j].w - mu) * r * lng[c0 + 3] + lnb[c0 + 3]);
      *(bf16x4*)(lnout + (size_t)token * 768 + c0) = o4;
    }
    return;
  }
  __shared__ float tile[32][33];
  const int d = (i >= 6912) ? 1 : 0;
  i -= d * 6912;
  const float* W; bf16* Wt; int K, N, nt;
  if (i < 1728)      { W = d ? qw1 : qw0; Wt = d ? qt1 : qt0; K = 768;  N = 2304; nt = 72; }
  else if (i < 2304) { i -= 1728; W = d ? pw1 : pw0; Wt = d ? pt1 : pt0; K = 768; N = 768; nt = 24; }
  else if (i < 4608) { i -= 2304; W = d ? w11 : w10; Wt = d ? t11 : t10; K = 768; N = 3072; nt = 96; }
  else               { i -= 4608; W = d ? w21 : w20; Wt = d ? t21 : t20; K = 3072; N = 768; nt = 24; }
  const int n0 = (i % nt) * 32, k0 = (i / nt) * 32;
  const int tx = threadIdx.x & 31, ty = threadIdx.x >> 5;
#pragma unroll
  for (int j = ty; j < 32; j += 8)
    tile[j][tx] = W[(size_t)(k0 + j) * N + n0 + tx];
  __syncthreads();
#pragma unroll
  for (int j = ty; j < 32; j += 8)
    Wt[(size_t)(n0 + j) * K + k0 + tx] = (bf16)tile[tx][j];
}

// ======== 256xBN-tile 8-wave deep-pipelined GEMM: C = A[M,K] @ Bt[N,K]^T ========
// (verified best config: BM=256, BN=192, BK=64, 112 KiB LDS — R11, 418 µs)
template <int EPI, int NF>
__global__ __launch_bounds__(512, 2) void gemm256_k(
    const bf16* __restrict__ A, int lda,
    const bf16* __restrict__ Bt, int ldb,
    const float* __restrict__ bias,
    void* __restrict__ outp, int ldc, int K, bf16* __restrict__ vtout,
    size_t pstride) {
  extern __shared__ __align__(16) bf16 smem[];
  bf16* As = smem;                 // [2][256][64]
  bf16* Bs = smem + 32768;         // [2][NF*64][64]
  const int BROWS = NF * 64;

  const int t = threadIdx.x, wave = t >> 6, lane = t & 63;
  const int g = lane >> 4, l16 = lane & 15;
  const int wm = wave >> 2, wn = wave & 3;
  const int row0 = blockIdx.y * 256, col0 = blockIdx.x * (NF * 64);
  const int koff = (EPI == 4) ? blockIdx.z * K : 0;
  const int KT = K >> 6;

  f32x4 acc[8][NF];
#pragma unroll
  for (int m = 0; m < 8; m++)
#pragma unroll
    for (int n = 0; n < NF; n++) acc[m][n] = f32x4{0.f, 0.f, 0.f, 0.f};

  const int s_r = t >> 3, s_sl = t & 7;

  auto stage = [&](int kt, int tb) {
    const int k0 = koff + (kt << 6);
#pragma unroll
    for (int l = 0; l < 4; ++l) {
      const int row = l * 64 + s_r;
      const int swz = (s_sl ^ (row & 7)) << 3;
      GLOAD16(A + (size_t)(row0 + row) * lda + k0 + swz,
              As + tb * 16384 + row * 64 + (s_sl << 3));
    }
#pragma unroll
    for (int l = 0; l < NF; ++l) {
      const int row = l * 64 + s_r;
      const int swz = (s_sl ^ (row & 7)) << 3;
      GLOAD16(Bt + (size_t)(col0 + row) * ldb + k0 + swz,
              Bs + tb * (BROWS * 64) + row * 64 + (s_sl << 3));
    }
  };

  stage(0, 0);
  __syncthreads();

  for (int j = 0; j < KT; ++j) {
    const int p = j & 1;
    if (j + 1 < KT) stage(j + 1, p ^ 1);

    bf16x8 bfr[NF][2];
#pragma unroll
    for (int n = 0; n < NF; ++n)
#pragma unroll
      for (int kk = 0; kk < 2; ++kk) {
        const int r = wn * (NF * 16) + n * 16 + l16;
        bfr[n][kk] = *(const bf16x8*)(Bs + p * (BROWS * 64) + r * 64 +
                                      ((((kk << 2) + g) ^ (r & 7)) << 3));
      }
#pragma unroll
    for (int quad = 0; quad < 4; ++quad) {
      bf16x8 af[2][2];
#pragma unroll
      for (int mm = 0; mm < 2; ++mm)
#pragma unroll
        for (int kk = 0; kk < 2; ++kk) {
          const int r = wm * 128 + (quad * 2 + mm) * 16 + l16;
          af[mm][kk] = *(const bf16x8*)(As + p * 16384 + r * 64 +
                                        ((((kk << 2) + g) ^ (r & 7)) << 3));
        }
      __builtin_amdgcn_s_barrier();
      __builtin_amdgcn_s_setprio(1);
#pragma unroll
      for (int mm = 0; mm < 2; ++mm)
#pragma unroll
        for (int n = 0; n < NF; ++n)
#pragma unroll
          for (int kk = 0; kk < 2; ++kk)
            acc[quad * 2 + mm][n] = __builtin_amdgcn_mfma_f32_16x16x32_bf16(
                bfr[n][kk], af[mm][kk], acc[quad * 2 + mm][n], 0, 0, 0);
      __builtin_amdgcn_s_setprio(0);
    }
    __syncthreads();   // gate: vmcnt(0)+lgkmcnt(0)+barrier (visibility + overwrite)
  }

  const int rowb = row0 + wm * 128 + l16;
  const int colb = col0 + wn * (NF * 16) + (g << 2);
  bf16* outb = (bf16*)outp;
  if constexpr (EPI == 4) outb += (size_t)blockIdx.z * pstride;
#pragma unroll
  for (int m = 0; m < 8; ++m) {
    const int row = rowb + m * 16;
#pragma unroll
    for (int n = 0; n < NF; ++n) {
      const int c0 = colb + n * 16;
      f32x4 v = acc[m][n];
      if constexpr (EPI != 4) {
        const float4 b4 = *(const float4*)(bias + c0);
        v[0] += b4.x; v[1] += b4.y; v[2] += b4.z; v[3] += b4.w;
      }
      if constexpr (EPI == 1) {
        v[0] = gelu_f(v[0]); v[1] = gelu_f(v[1]);
        v[2] = gelu_f(v[2]); v[3] = gelu_f(v[3]);
      }
      bf16x4 o4;
      o4[0] = (bf16)v[0]; o4[1] = (bf16)v[1]; o4[2] = (bf16)v[2]; o4[3] = (bf16)v[3];
      *(bf16x4*)(outb + (size_t)row * ldc + c0) = o4;
      if constexpr (EPI == 0) {
        if (c0 >= 1536) {   // fused V-transpose side-write
          const int bq = row >> 10, q = row & 1023;
          const int hd = c0 - 1536, h = hd >> 6, dd = hd & 63;
          bf16* vb = vtout + (size_t)(bq * 12 + h) * 65536 + (size_t)dd * 1024 + q;
          vb[0] = o4[0]; vb[1024] = o4[1]; vb[2048] = o4[2]; vb[3072] = o4[3];
        }
      }
    }
  }
}

// ------ split-K reduce + optional fused LayerNorm of the result ------
template <int NP, int MODE, bool LN>
__global__ __launch_bounds__(256) void reduce_ln_k(
    const bf16* __restrict__ pbuf, const float* __restrict__ bias,
    const float* __restrict__ res, const float* __restrict__ res2,
    float* __restrict__ xout, const float* __restrict__ g,
    const float* __restrict__ b, bf16* __restrict__ lnout) {
  const int token = blockIdx.x * 4 + (threadIdx.x >> 6);
  const int lane  = threadIdx.x & 63;
  float o[12];
  float s = 0.f, ss = 0.f;
#pragma unroll
  for (int j = 0; j < 3; j++) {
    const int c0 = (lane + j * 64) * 4;
    const size_t idx = (size_t)token * 768 + c0;
    const float4 b4 = *(const float4*)(bias + c0);
    float a0 = b4.x, a1 = b4.y, a2 = b4.z, a3 = b4.w;
#pragma unroll
    for (int sp = 0; sp < NP; sp++) {
      const bf16x4 pp = *(const bf16x4*)(pbuf + (size_t)sp * 3145728 + idx);
      a0 += (float)pp[0]; a1 += (float)pp[1]; a2 += (float)pp[2]; a3 += (float)pp[3];
    }
    const float4 r4 = *(const float4*)(res + idx);
    float4 ov;
    if constexpr (MODE == 0) {
      ov.x = a0 + r4.x; ov.y = a1 + r4.y; ov.z = a2 + r4.z; ov.w = a3 + r4.w;
    } else {
      const float4 r2 = *(const float4*)(res2 + idx);
      ov.x = 0.5f * (a0 + r4.x + r2.x); ov.y = 0.5f * (a1 + r4.y + r2.y);
      ov.z = 0.5f * (a2 + r4.z + r2.z); ov.w = 0.5f * (a3 + r4.w + r2.w);
    }
    *(float4*)(xout + idx) = ov;
    o[j * 4 + 0] = ov.x; o[j * 4 + 1] = ov.y; o[j * 4 + 2] = ov.z; o[j * 4 + 3] = ov.w;
    s  += ov.x + ov.y + ov.z + ov.w;
    ss += ov.x * ov.x + ov.y * ov.y + ov.z * ov.z + ov.w * ov.w;
  }
  if constexpr (LN) {
#pragma unroll
    for (int off = 32; off > 0; off >>= 1) { s += __shfl_xor(s, off); ss += __shfl_xor(ss, off); }
    const float mu  = s * (1.f / 768.f);
    const float var = ss * (1.f / 768.f) - mu * mu;
    const float r   = rsqrtf(var + 1e-5f);
#pragma unroll
    for (int j = 0; j < 3; j++) {
      const int c0 = (lane + j * 64) * 4;
      bf16x4 o4;
      o4[0] = (bf16)((o[j * 4 + 0] - mu) * r * g[c0 + 0] + b[c0 + 0]);
      o4[1] = (bf16)((o[j * 4 + 1] - mu) * r * g[c0 + 1] + b[c0 + 1]);
      o4[2] = (bf16)((o[j * 4 + 2] - mu) * r * g[c0 + 2] + b[c0 + 2]);
      o4[3] = (bf16)((o[j * 4 + 3] - mu) * r * g[c0 + 3] + b[c0 + 3]);
      *(bf16x4*)(lnout + (size_t)token * 768 + c0) = o4;
    }
  }
}

// ---- fused attention, SINGLE-PASS: QK^T once, unnormalized bf16 P in padded LDS,
// row sums accumulated online, coalesced normalized P writeout, PV from LDS.
// 512 threads = 8 waves = 4 q-groups x 2 kv/d-halves; LDS 145.5 KB, 1 block/CU.
__global__ __launch_bounds__(512) void fattn_k(const bf16* __restrict__ qkv,
                                               const bf16* __restrict__ vT,
                                               float* __restrict__ attn,
                                               bf16* __restrict__ aout) {
  extern __shared__ __align__(16) char fsm[];
  bf16*  Ks = (bf16*)fsm;                      // [128][64], source-swizzled
  bf16*  Pl = (bf16*)(fsm + 16384);            // [64][1032] padded rows (2064B stride)
  float* Sr = (float*)(fsm + 16384 + 132096);  // [8][16] per-wave row-sum partials

  const float S2 = 0.18033688011112042f;  // 0.125 * log2(e)

  const int bid = blockIdx.x;
  const int xcd = bid & 7, within = bid >> 3;
  const int bh = xcd * 6 + (within >> 4);
  const int qb = within & 15;
  const int b = bh / 12, h = bh % 12;

  const int t = threadIdx.x, w = t >> 6, lane = t & 63;
  const int g = lane >> 4, l16 = lane & 15;
  const int qg = w & 3, kvh = w >> 2;
  const int q0 = qb * 64;
  const int qrow = qg * 16 + l16;

  const bf16* qbp = qkv + (size_t)b * 1024 * 2304 + h * 64;
  const bf16* kbp = qbp + 768;
  const bf16* vt = vT + (size_t)bh * 65536;
  float* Pout = attn + (size_t)bh * 1048576;

  bf16x8 qf[2];
#pragma unroll
  for (int kk = 0; kk < 2; kk++)
    qf[kk] = *(const bf16x8*)(qbp + (size_t)(q0 + qrow) * 2304 + kk * 32 + g * 8);

  const int kvr = t >> 3, sl = t & 7;
  float psum = 0.f;

  // ---- single QK pass: S^T via mfma(K,Q), exp2 -> Pl (bf16), online row sums ----
  for (int kv0 = 0; kv0 < 1024; kv0 += 128) {
#pragma unroll
    for (int i = 0; i < 2; i++) {
      const int kvl = i * 64 + kvr;
      GLOAD16(kbp + (size_t)(kv0 + kvl) * 2304 + (sl ^ (kvl & 7)) * 8,
              Ks + i * 4096 + t * 8);
    }
    __syncthreads();
    f32x4 st[4];
#pragma unroll
    for (int mkf = 0; mkf < 4; mkf++) st[mkf] = f32x4{0.f, 0.f, 0.f, 0.f};
    __builtin_amdgcn_s_setprio(1);
#pragma unroll
    for (int kk = 0; kk < 2; kk++) {
#pragma unroll
      for (int mkf = 0; mkf < 4; mkf++) {
        const int kv = kvh * 64 + mkf * 16 + l16;
        const bf16x8 kf = *(const bf16x8*)(Ks + ((kv * 64 + kk * 32 + g * 8) ^ ((kv & 7) << 3)));
        st[mkf] = __builtin_amdgcn_mfma_f32_16x16x32_bf16(kf, qf[kk], st[mkf], 0, 0, 0);
      }
    }
    __builtin_amdgcn_s_setprio(0);
#pragma unroll
    for (int mkf = 0; mkf < 4; mkf++) {
      f32x4 pv;
      pv[0] = exp2f(st[mkf][0] * S2);
      pv[1] = exp2f(st[mkf][1] * S2);
      pv[2] = exp2f(st[mkf][2] * S2);
      pv[3] = exp2f(st[mkf][3] * S2);
      psum += pv[0] + pv[1] + pv[2] + pv[3];
      bf16x4 pb;
      pb[0] = (bf16)pv[0]; pb[1] = (bf16)pv[1]; pb[2] = (bf16)pv[2]; pb[3] = (bf16)pv[3];
      *(bf16x4*)(Pl + qrow * 1032 + kv0 + kvh * 64 + mkf * 16 + g * 4) = pb;
    }
    __syncthreads();   // Ks reads done before next stage overwrites
  }

  // ---- row-sum reduce: over g via shfl, over kv-halves via Sr ----
  psum += __shfl_xor(psum, 16);
  psum += __shfl_xor(psum, 32);
  if (g == 0) Sr[w * 16 + l16] = psum;
  __syncthreads();

  const float invl = 1.f / (Sr[qg * 16 + l16] + Sr[(qg + 4) * 16 + l16]);

  // ---- coalesced normalized P writeout: wave w handles rows {w, w+8, ...} ----
#pragma unroll
  for (int j = 0; j < 8; j++) {
    const int row = j * 8 + w;
    const float invr = 1.f / (Sr[(row >> 4) * 16 + (row & 15)] +
                              Sr[((row >> 4) + 4) * 16 + (row & 15)]);
    float* dst = Pout + (size_t)(q0 + row) * 1024;
#pragma unroll
    for (int c = 0; c < 4; c++) {
      const int col = (c * 64 + lane) * 4;
      const bf16x4 pb = *(const bf16x4*)(Pl + row * 1032 + col);
      f32x4 v;
      v[0] = (float)pb[0] * invr; v[1] = (float)pb[1] * invr;
      v[2] = (float)pb[2] * invr; v[3] = (float)pb[3] * invr;
      __builtin_nontemporal_store(v, (f32x4*)(dst + col));
    }
  }

  // ---- PV from Pl: wave (qg, dh) computes q-group x d-half; scale by invl ----
  const int dh = kvh;
  f32x4 oacc[2];
  oacc[0] = f32x4{0.f, 0.f, 0.f, 0.f};
  oacc[1] = f32x4{0.f, 0.f, 0.f, 0.f};
  for (int kv = 0; kv < 1024; kv += 32) {
    const bf16x8 pf = *(const bf16x8*)(Pl + qrow * 1032 + kv + g * 8);
    __builtin_amdgcn_s_setprio(1);
#pragma unroll
    for (int nd = 0; nd < 2; nd++) {
      const bf16x8 vf =
          *(const bf16x8*)(vt + (size_t)(dh * 32 + nd * 16 + l16) * 1024 + kv + g * 8);
      oacc[nd] = __builtin_amdgcn_mfma_f32_16x16x32_bf16(vf, pf, oacc[nd], 0, 0, 0);
    }
    __builtin_amdgcn_s_setprio(0);
  }

  {
    const int q = q0 + qrow;
    bf16* ob = aout + (size_t)(b * 1024 + q) * 768 + h * 64 + dh * 32 + g * 4;
#pragma unroll
    for (int nd = 0; nd < 2; nd++) {
      bf16x4 o4;
      o4[0] = (bf16)(oacc[nd][0] * invl); o4[1] = (bf16)(oacc[nd][1] * invl);
      o4[2] = (bf16)(oacc[nd][2] * invl); o4[3] = (bf16)(oacc[nd][3] * invl);
      *(bf16x4*)(ob + nd * 16) = o4;
    }
  }
}

// ---------------- host ----------------
extern "C" void kernel_launch(void* const* d_in, const int* in_sizes, int n_in,
                              void* d_out, int out_size, void* d_ws, size_t ws_size,
                              hipStream_t stream) {
  (void)in_sizes; (void)n_in; (void)out_size; (void)ws_size;
  const float* x = (const float*)d_in[0];
#define IN(d, i) ((const float*)d_in[1 + (d) * 12 + (i)])
  float* outF = (float*)d_out;
  float* attnp[2] = {outF + 3145728, outF + 3145728 + 50331648};

  // dynamic LDS: 112 KiB for GEMMs, 145.5 KiB for single-pass fattn
  const int kLds = 114688;
  const int kLdsAttn = 148992;
  hipFuncSetAttribute((const void*)gemm256_k<0, 3>,
                      hipFuncAttributeMaxDynamicSharedMemorySize, kLds);
  hipFuncSetAttribute((const void*)gemm256_k<1, 3>,
                      hipFuncAttributeMaxDynamicSharedMemorySize, kLds);
  hipFuncSetAttribute((const void*)gemm256_k<4, 3>,
                      hipFuncAttributeMaxDynamicSharedMemorySize, kLds);
  hipFuncSetAttribute((const void*)fattn_k,
                      hipFuncAttributeMaxDynamicSharedMemorySize, kLdsAttn);

  char* p = (char*)d_ws;
  auto alloc = [&](size_t bytes) { void* r = p; p += bytes; return r; };
  bf16 *qkv_wt[2], *proj_wt[2], *w1t[2], *w2t[2];
  for (int d = 0; d < 2; d++) {
    qkv_wt[d]  = (bf16*)alloc((size_t)2304 * 768 * 2);
    proj_wt[d] = (bf16*)alloc((size_t)768 * 768 * 2);
    w1t[d]     = (bf16*)alloc((size_t)3072 * 768 * 2);
    w2t[d]     = (bf16*)alloc((size_t)768 * 3072 * 2);
  }
  // hbuf+qkvb form one contiguous 25.17 MB region; reused as up to 4 bf16
  // split-K partials (4 x 3145728 elems) while both buffers are dead.
  bf16*  hbuf = (bf16*)alloc((size_t)4096 * 768 * 2);
  bf16*  qkvb = (bf16*)alloc((size_t)4096 * 2304 * 2);
  bf16*  pbuf = hbuf;
  bf16*  vT   = (bf16*)alloc((size_t)48 * 64 * 1024 * 2);
  bf16*  aout = (bf16*)alloc((size_t)4096 * 768 * 2);
  bf16*  hid  = (bf16*)alloc((size_t)4096 * 3072 * 2);
  float* xa   = (float*)alloc((size_t)4096 * 768 * 4);
  float* xb   = (float*)alloc((size_t)4096 * 768 * 4);

  transpose_all_k<<<14848, 256, 0, stream>>>(
      IN(0, 0), qkv_wt[0], IN(0, 2), proj_wt[0], IN(0, 8), w1t[0], IN(0, 10), w2t[0],
      IN(1, 0), qkv_wt[1], IN(1, 2), proj_wt[1], IN(1, 8), w1t[1], IN(1, 10), w2t[1],
      x, IN(0, 4), IN(0, 5), hbuf);

  // ---- layer 0 attention: xa = x + attn0(hbuf); also LN1_1(xa) -> hbuf ----
  gemm256_k<0, 3><<<dim3(12, 16), 512, kLds, stream>>>(hbuf, 768, qkv_wt[0], 768, IN(0, 1),
                                                       qkvb, 2304, 768, vT, 0);
  fattn_k<<<768, 512, kLdsAttn, stream>>>(qkvb, vT, attnp[0], aout);
  gemm256_k<4, 3><<<dim3(4, 16, 4), 512, kLds, stream>>>(aout, 768, proj_wt[0], 768, nullptr,
                                                         pbuf, 768, 192, nullptr, 3145728);
  reduce_ln_k<4, 0, true><<<1024, 256, 0, stream>>>(pbuf, IN(0, 3), x, nullptr,
                                                    xa, IN(1, 4), IN(1, 5), hbuf);
  // ---- layer 1 attention: xb = xa + attn1(hbuf); also LN2_1(xb) -> hbuf ----
  gemm256_k<0, 3><<<dim3(12, 16), 512, kLds, stream>>>(hbuf, 768, qkv_wt[1], 768, IN(1, 1),
                                                       qkvb, 2304, 768, vT, 0);
  fattn_k<<<768, 512, kLdsAttn, stream>>>(qkvb, vT, attnp[1], aout);
  gemm256_k<4, 3><<<dim3(4, 16, 4), 512, kLds, stream>>>(aout, 768, proj_wt[1], 768, nullptr,
                                                         pbuf, 768, 192, nullptr, 3145728);
  reduce_ln_k<4, 0, true><<<1024, 256, 0, stream>>>(pbuf, IN(1, 3), xa, nullptr,
                                                    xb, IN(1, 6), IN(1, 7), hbuf);
  // ---- layer 1 MLP + blend: xa = 0.5*(xa + xb + mlp1(hbuf)); LN2_0(xa) -> hbuf ----
  gemm256_k<1, 3><<<dim3(16, 16), 512, kLds, stream>>>(hbuf, 768, w1t[1], 768, IN(1, 9),
                                                       hid, 3072, 768, nullptr, 0);
  gemm256_k<4, 3><<<dim3(4, 16, 4), 512, kLds, stream>>>(hid, 3072, w2t[1], 3072, nullptr,
                                                         pbuf, 768, 768, nullptr, 3145728);
  reduce_ln_k<4, 1, true><<<1024, 256, 0, stream>>>(pbuf, IN(1, 11), xb, xa,
                                                    xa, IN(0, 6), IN(0, 7), hbuf);
  // ---- layer 0 MLP: out = xa + mlp0(hbuf) ----
  gemm256_k<1, 3><<<dim3(16, 16), 512, kLds, stream>>>(hbuf, 768, w1t[0], 768, IN(0, 9),
                                                       hid, 3072, 768, nullptr, 0);
  gemm256_k<4, 3><<<dim3(4, 16, 4), 512, kLds, stream>>>(hid, 3072, w2t[0], 3072, nullptr,
                                                         pbuf, 768, 768, nullptr, 3145728);
  reduce_ln_k<4, 0, false><<<1024, 256, 0, stream>>>(pbuf, IN(0, 11), xa, nullptr,
                                                     outF, nullptr, nullptr, nullptr);
#undef IN
}

// Round 17
// 418.373 us; speedup vs baseline: 1.0985x; 1.0985x over previous
//
#include <hip/hip_runtime.h>
#include <hip/hip_bf16.h>
#include <stdint.h>

typedef __bf16 bf16;
typedef __bf16 bf16x8 __attribute__((ext_vector_type(8)));
typedef __bf16 bf16x4 __attribute__((ext_vector_type(4)));
typedef float  f32x4  __attribute__((ext_vector_type(4)));

#define GLOAD16(gsrc, ldst)                                                        \
  __builtin_amdgcn_global_load_lds(                                               \
      (const __attribute__((address_space(1))) void*)(gsrc),                      \
      (__attribute__((address_space(3))) void*)(ldst), 16, 0, 0)

__device__ __forceinline__ float gelu_f(float v) {
  return 0.5f * v * (1.0f + erff(v * 0.70710678118654752f));
}

// ---- batched transpose+cast for all 8 weights  +  fused ln0 (blocks >= 13824) ----
__global__ __launch_bounds__(256) void transpose_all_k(
    const float* __restrict__ qw0, bf16* __restrict__ qt0,
    const float* __restrict__ pw0, bf16* __restrict__ pt0,
    const float* __restrict__ w10, bf16* __restrict__ t10,
    const float* __restrict__ w20, bf16* __restrict__ t20,
    const float* __restrict__ qw1, bf16* __restrict__ qt1,
    const float* __restrict__ pw1, bf16* __restrict__ pt1,
    const float* __restrict__ w11, bf16* __restrict__ t11,
    const float* __restrict__ w21, bf16* __restrict__ t21,
    const float* __restrict__ x, const float* __restrict__ lng,
    const float* __restrict__ lnb, bf16* __restrict__ lnout) {
  int i = blockIdx.x;
  if (i >= 13824) {
    const int token = (i - 13824) * 4 + (threadIdx.x >> 6);
    const int lane  = threadIdx.x & 63;
    const float4* xp = (const float4*)(x + (size_t)token * 768);
    float4 v[3];
    float s = 0.f, ss = 0.f;
#pragma unroll
    for (int j = 0; j < 3; j++) {
      v[j] = xp[lane + j * 64];
      s  += v[j].x + v[j].y + v[j].z + v[j].w;
      ss += v[j].x * v[j].x + v[j].y * v[j].y + v[j].z * v[j].z + v[j].w * v[j].w;
    }
#pragma unroll
    for (int o = 32; o > 0; o >>= 1) { s += __shfl_xor(s, o); ss += __shfl_xor(ss, o); }
    const float mu  = s * (1.f / 768.f);
    const float var = ss * (1.f / 768.f) - mu * mu;
    const float r   = rsqrtf(var + 1e-5f);
#pragma unroll
    for (int j = 0; j < 3; j++) {
      const int c0 = (lane + j * 64) * 4;
      bf16x4 o4;
      o4[0] = (bf16)((v[j].x - mu) * r * lng[c0 + 0] + lnb[c0 + 0]);
      o4[1] = (bf16)((v[j].y - mu) * r * lng[c0 + 1] + lnb[c0 + 1]);
      o4[2] = (bf16)((v[j].z - mu) * r * lng[c0 + 2] + lnb[c0 + 2]);
      o4[3] = (bf16)((v[j].w - mu) * r * lng[c0 + 3] + lnb[c0 + 3]);
      *(bf16x4*)(lnout + (size_t)token * 768 + c0) = o4;
    }
    return;
  }
  __shared__ float tile[32][33];
  const int d = (i >= 6912) ? 1 : 0;
  i -= d * 6912;
  const float* W; bf16* Wt; int K, N, nt;
  if (i < 1728)      { W = d ? qw1 : qw0; Wt = d ? qt1 : qt0; K = 768;  N = 2304; nt = 72; }
  else if (i < 2304) { i -= 1728; W = d ? pw1 : pw0; Wt = d ? pt1 : pt0; K = 768; N = 768; nt = 24; }
  else if (i < 4608) { i -= 2304; W = d ? w11 : w10; Wt = d ? t11 : t10; K = 768; N = 3072; nt = 96; }
  else               { i -= 4608; W = d ? w21 : w20; Wt = d ? t21 : t20; K = 3072; N = 768; nt = 24; }
  const int n0 = (i % nt) * 32, k0 = (i / nt) * 32;
  const int tx = threadIdx.x & 31, ty = threadIdx.x >> 5;
#pragma unroll
  for (int j = ty; j < 32; j += 8)
    tile[j][tx] = W[(size_t)(k0 + j) * N + n0 + tx];
  __syncthreads();
#pragma unroll
  for (int j = ty; j < 32; j += 8)
    Wt[(size_t)(n0 + j) * K + k0 + tx] = (bf16)tile[tx][j];
}

// ======== 256xBN-tile 8-wave deep-pipelined GEMM: C = A[M,K] @ Bt[N,K]^T ========
// (verified best config: BM=256, BN=192, BK=64, 112 KiB LDS — R11, 418 µs)
template <int EPI, int NF>
__global__ __launch_bounds__(512, 2) void gemm256_k(
    const bf16* __restrict__ A, int lda,
    const bf16* __restrict__ Bt, int ldb,
    const float* __restrict__ bias,
    void* __restrict__ outp, int ldc, int K, bf16* __restrict__ vtout,
    size_t pstride) {
  extern __shared__ __align__(16) bf16 smem[];
  bf16* As = smem;                 // [2][256][64]
  bf16* Bs = smem + 32768;         // [2][NF*64][64]
  const int BROWS = NF * 64;

  const int t = threadIdx.x, wave = t >> 6, lane = t & 63;
  const int g = lane >> 4, l16 = lane & 15;
  const int wm = wave >> 2, wn = wave & 3;
  const int row0 = blockIdx.y * 256, col0 = blockIdx.x * (NF * 64);
  const int koff = (EPI == 4) ? blockIdx.z * K : 0;
  const int KT = K >> 6;

  f32x4 acc[8][NF];
#pragma unroll
  for (int m = 0; m < 8; m++)
#pragma unroll
    for (int n = 0; n < NF; n++) acc[m][n] = f32x4{0.f, 0.f, 0.f, 0.f};

  const int s_r = t >> 3, s_sl = t & 7;

  auto stage = [&](int kt, int tb) {
    const int k0 = koff + (kt << 6);
#pragma unroll
    for (int l = 0; l < 4; ++l) {
      const int row = l * 64 + s_r;
      const int swz = (s_sl ^ (row & 7)) << 3;
      GLOAD16(A + (size_t)(row0 + row) * lda + k0 + swz,
              As + tb * 16384 + row * 64 + (s_sl << 3));
    }
#pragma unroll
    for (int l = 0; l < NF; ++l) {
      const int row = l * 64 + s_r;
      const int swz = (s_sl ^ (row & 7)) << 3;
      GLOAD16(Bt + (size_t)(col0 + row) * ldb + k0 + swz,
              Bs + tb * (BROWS * 64) + row * 64 + (s_sl << 3));
    }
  };

  stage(0, 0);
  __syncthreads();

  for (int j = 0; j < KT; ++j) {
    const int p = j & 1;
    if (j + 1 < KT) stage(j + 1, p ^ 1);

    bf16x8 bfr[NF][2];
#pragma unroll
    for (int n = 0; n < NF; ++n)
#pragma unroll
      for (int kk = 0; kk < 2; ++kk) {
        const int r = wn * (NF * 16) + n * 16 + l16;
        bfr[n][kk] = *(const bf16x8*)(Bs + p * (BROWS * 64) + r * 64 +
                                      ((((kk << 2) + g) ^ (r & 7)) << 3));
      }
#pragma unroll
    for (int quad = 0; quad < 4; ++quad) {
      bf16x8 af[2][2];
#pragma unroll
      for (int mm = 0; mm < 2; ++mm)
#pragma unroll
        for (int kk = 0; kk < 2; ++kk) {
          const int r = wm * 128 + (quad * 2 + mm) * 16 + l16;
          af[mm][kk] = *(const bf16x8*)(As + p * 16384 + r * 64 +
                                        ((((kk << 2) + g) ^ (r & 7)) << 3));
        }
      __builtin_amdgcn_s_barrier();
      __builtin_amdgcn_s_setprio(1);
#pragma unroll
      for (int mm = 0; mm < 2; ++mm)
#pragma unroll
        for (int n = 0; n < NF; ++n)
#pragma unroll
          for (int kk = 0; kk < 2; ++kk)
            acc[quad * 2 + mm][n] = __builtin_amdgcn_mfma_f32_16x16x32_bf16(
                bfr[n][kk], af[mm][kk], acc[quad * 2 + mm][n], 0, 0, 0);
      __builtin_amdgcn_s_setprio(0);
    }
    __syncthreads();   // gate: vmcnt(0)+lgkmcnt(0)+barrier (visibility + overwrite)
  }

  const int rowb = row0 + wm * 128 + l16;
  const int colb = col0 + wn * (NF * 16) + (g << 2);
  bf16* outb = (bf16*)outp;
  if constexpr (EPI == 4) outb += (size_t)blockIdx.z * pstride;
#pragma unroll
  for (int m = 0; m < 8; ++m) {
    const int row = rowb + m * 16;
#pragma unroll
    for (int n = 0; n < NF; ++n) {
      const int c0 = colb + n * 16;
      f32x4 v = acc[m][n];
      if constexpr (EPI != 4) {
        const float4 b4 = *(const float4*)(bias + c0);
        v[0] += b4.x; v[1] += b4.y; v[2] += b4.z; v[3] += b4.w;
      }
      if constexpr (EPI == 1) {
        v[0] = gelu_f(v[0]); v[1] = gelu_f(v[1]);
        v[2] = gelu_f(v[2]); v[3] = gelu_f(v[3]);
      }
      bf16x4 o4;
      o4[0] = (bf16)v[0]; o4[1] = (bf16)v[1]; o4[2] = (bf16)v[2]; o4[3] = (bf16)v[3];
      *(bf16x4*)(outb + (size_t)row * ldc + c0) = o4;
      if constexpr (EPI == 0) {
        if (c0 >= 1536) {   // fused V-transpose side-write
          const int bq = row >> 10, q = row & 1023;
          const int hd = c0 - 1536, h = hd >> 6, dd = hd & 63;
          bf16* vb = vtout + (size_t)(bq * 12 + h) * 65536 + (size_t)dd * 1024 + q;
          vb[0] = o4[0]; vb[1024] = o4[1]; vb[2048] = o4[2]; vb[3072] = o4[3];
        }
      }
    }
  }
}

// ------ split-K reduce + optional fused LayerNorm of the result ------
template <int NP, int MODE, bool LN>
__global__ __launch_bounds__(256) void reduce_ln_k(
    const bf16* __restrict__ pbuf, const float* __restrict__ bias,
    const float* __restrict__ res, const float* __restrict__ res2,
    float* __restrict__ xout, const float* __restrict__ g,
    const float* __restrict__ b, bf16* __restrict__ lnout) {
  const int token = blockIdx.x * 4 + (threadIdx.x >> 6);
  const int lane  = threadIdx.x & 63;
  float o[12];
  float s = 0.f, ss = 0.f;
#pragma unroll
  for (int j = 0; j < 3; j++) {
    const int c0 = (lane + j * 64) * 4;
    const size_t idx = (size_t)token * 768 + c0;
    const float4 b4 = *(const float4*)(bias + c0);
    float a0 = b4.x, a1 = b4.y, a2 = b4.z, a3 = b4.w;
#pragma unroll
    for (int sp = 0; sp < NP; sp++) {
      const bf16x4 pp = *(const bf16x4*)(pbuf + (size_t)sp * 3145728 + idx);
      a0 += (float)pp[0]; a1 += (float)pp[1]; a2 += (float)pp[2]; a3 += (float)pp[3];
    }
    const float4 r4 = *(const float4*)(res + idx);
    float4 ov;
    if constexpr (MODE == 0) {
      ov.x = a0 + r4.x; ov.y = a1 + r4.y; ov.z = a2 + r4.z; ov.w = a3 + r4.w;
    } else {
      const float4 r2 = *(const float4*)(res2 + idx);
      ov.x = 0.5f * (a0 + r4.x + r2.x); ov.y = 0.5f * (a1 + r4.y + r2.y);
      ov.z = 0.5f * (a2 + r4.z + r2.z); ov.w = 0.5f * (a3 + r4.w + r2.w);
    }
    *(float4*)(xout + idx) = ov;
    o[j * 4 + 0] = ov.x; o[j * 4 + 1] = ov.y; o[j * 4 + 2] = ov.z; o[j * 4 + 3] = ov.w;
    s  += ov.x + ov.y + ov.z + ov.w;
    ss += ov.x * ov.x + ov.y * ov.y + ov.z * ov.z + ov.w * ov.w;
  }
  if constexpr (LN) {
#pragma unroll
    for (int off = 32; off > 0; off >>= 1) { s += __shfl_xor(s, off); ss += __shfl_xor(ss, off); }
    const float mu  = s * (1.f / 768.f);
    const float var = ss * (1.f / 768.f) - mu * mu;
    const float r   = rsqrtf(var + 1e-5f);
#pragma unroll
    for (int j = 0; j < 3; j++) {
      const int c0 = (lane + j * 64) * 4;
      bf16x4 o4;
      o4[0] = (bf16)((o[j * 4 + 0] - mu) * r * g[c0 + 0] + b[c0 + 0]);
      o4[1] = (bf16)((o[j * 4 + 1] - mu) * r * g[c0 + 1] + b[c0 + 1]);
      o4[2] = (bf16)((o[j * 4 + 2] - mu) * r * g[c0 + 2] + b[c0 + 2]);
      o4[3] = (bf16)((o[j * 4 + 3] - mu) * r * g[c0 + 3] + b[c0 + 3]);
      *(bf16x4*)(lnout + (size_t)token * 768 + c0) = o4;
    }
  }
}

// ---- fused attention: S^T via mfma(K,Q), 2-pass softmax (no max), coalesced P out ----
__global__ __launch_bounds__(256) void fattn_k(const bf16* __restrict__ qkv,
                                               const bf16* __restrict__ vT,
                                               float* __restrict__ attn,
                                               bf16* __restrict__ aout) {
  __shared__ __align__(16) bf16  Ks[128 * 64];   // 16 KB, source-swizzled
  __shared__ __align__(16) float Pf[64 * 128];   // 32 KB, slot-swizzled

  const float S2 = 0.18033688011112042f;  // 0.125 * log2(e)

  const int bid = blockIdx.x;
  const int xcd = bid & 7, within = bid >> 3;
  const int bh = xcd * 6 + (within >> 4);
  const int qb = within & 15;
  const int b = bh / 12, h = bh % 12;

  const int t = threadIdx.x, w = t >> 6, lane = t & 63;
  const int g = lane >> 4, l16 = lane & 15;
  const int q0 = qb * 64;

  const bf16* qbp = qkv + (size_t)b * 1024 * 2304 + h * 64;
  const bf16* kbp = qbp + 768;
  const bf16* vt = vT + (size_t)bh * 65536;
  float* Pout = attn + (size_t)bh * 1048576;

  bf16x8 qf[2];
#pragma unroll
  for (int kk = 0; kk < 2; kk++)
    qf[kk] = *(const bf16x8*)(qbp + (size_t)(q0 + w * 16 + l16) * 2304 + kk * 32 + g * 8);

  const int kvr = t >> 3, sl = t & 7;

  float l_run = 0.f;

  // ---------------- pass 1: row sum of exp2(S*S2) ----------------
  for (int kv0 = 0; kv0 < 1024; kv0 += 128) {
#pragma unroll
    for (int i = 0; i < 4; i++) {
      const int kvl = i * 32 + kvr;
      GLOAD16(kbp + (size_t)(kv0 + kvl) * 2304 + (sl ^ (kvl & 7)) * 8,
              Ks + i * 2048 + t * 8);
    }
    __syncthreads();
    f32x4 st[8];
#pragma unroll
    for (int mk = 0; mk < 8; mk++) st[mk] = f32x4{0.f, 0.f, 0.f, 0.f};
    __builtin_amdgcn_s_setprio(1);
#pragma unroll
    for (int kk = 0; kk < 2; kk++) {
#pragma unroll
      for (int mk = 0; mk < 8; mk++) {
        const int kv = mk * 16 + l16;
        const bf16x8 kf = *(const bf16x8*)(Ks + ((kv * 64 + kk * 32 + g * 8) ^ ((kv & 7) << 3)));
        st[mk] = __builtin_amdgcn_mfma_f32_16x16x32_bf16(kf, qf[kk], st[mk], 0, 0, 0);
      }
    }
    __builtin_amdgcn_s_setprio(0);
    __syncthreads();
    float sum = 0.f;
#pragma unroll
    for (int mk = 0; mk < 8; mk++)
#pragma unroll
      for (int r = 0; r < 4; r++) sum += exp2f(st[mk][r] * S2);
    sum += __shfl_xor(sum, 16);
    sum += __shfl_xor(sum, 32);
    l_run += sum;
  }

  const float invl = 1.f / l_run;

  f32x4 oacc[4];
#pragma unroll
  for (int nd = 0; nd < 4; nd++) oacc[nd] = f32x4{0.f, 0.f, 0.f, 0.f};

  const int ql = w * 16 + l16;
  const int cs = t & 31, rb = t >> 5;

  // ---------------- pass 2: recompute S, LDS-bounce P, coalesced write, PV ----
  for (int kv0 = 0; kv0 < 1024; kv0 += 128) {
#pragma unroll
    for (int i = 0; i < 4; i++) {
      const int kvl = i * 32 + kvr;
      GLOAD16(kbp + (size_t)(kv0 + kvl) * 2304 + (sl ^ (kvl & 7)) * 8,
              Ks + i * 2048 + t * 8);
    }
    __syncthreads();
    f32x4 st[8];
#pragma unroll
    for (int mk = 0; mk < 8; mk++) st[mk] = f32x4{0.f, 0.f, 0.f, 0.f};
    __builtin_amdgcn_s_setprio(1);
#pragma unroll
    for (int kk = 0; kk < 2; kk++) {
#pragma unroll
      for (int mk = 0; mk < 8; mk++) {
        const int kv = mk * 16 + l16;
        const bf16x8 kf = *(const bf16x8*)(Ks + ((kv * 64 + kk * 32 + g * 8) ^ ((kv & 7) << 3)));
        st[mk] = __builtin_amdgcn_mfma_f32_16x16x32_bf16(kf, qf[kk], st[mk], 0, 0, 0);
      }
    }
    __builtin_amdgcn_s_setprio(0);

    // normalized P -> Pf (16B slot = (mk*4+g) ^ (ql&7); bijective per row)
#pragma unroll
    for (int mk = 0; mk < 8; mk++) {
      f32x4 pv;
      pv[0] = exp2f(st[mk][0] * S2) * invl;
      pv[1] = exp2f(st[mk][1] * S2) * invl;
      pv[2] = exp2f(st[mk][2] * S2) * invl;
      pv[3] = exp2f(st[mk][3] * S2) * invl;
      *(f32x4*)(Pf + ql * 128 + ((((mk << 2) + g) ^ (ql & 7)) << 2)) = pv;
    }
    __syncthreads();

    // coalesced Pout copy: 512B-contiguous runs
#pragma unroll
    for (int j = 0; j < 8; j++) {
      const int row = j * 8 + rb;
      const f32x4 v = *(const f32x4*)(Pf + row * 128 + ((cs ^ (row & 7)) << 2));
      __builtin_nontemporal_store(
          v, (f32x4*)(Pout + (size_t)(q0 + row) * 1024 + kv0 + (cs << 2)));
    }

    // PV: bf16 A-frags rebuilt from Pf
#pragma unroll
    for (int kkv = 0; kkv < 4; kkv++) {
      const int s0 = (kkv << 3) + (g << 1);
      const f32x4 plo = *(const f32x4*)(Pf + ql * 128 + ((s0 ^ (ql & 7)) << 2));
      const f32x4 phi = *(const f32x4*)(Pf + ql * 128 + (((s0 + 1) ^ (ql & 7)) << 2));
      bf16x8 pf;
      pf[0] = (bf16)plo[0]; pf[1] = (bf16)plo[1]; pf[2] = (bf16)plo[2]; pf[3] = (bf16)plo[3];
      pf[4] = (bf16)phi[0]; pf[5] = (bf16)phi[1]; pf[6] = (bf16)phi[2]; pf[7] = (bf16)phi[3];
      bf16x8 vf[4];
#pragma unroll
      for (int nd = 0; nd < 4; nd++)
        vf[nd] = *(const bf16x8*)(vt + (size_t)(nd * 16 + l16) * 1024 + kv0 + kkv * 32 + g * 8);
      __builtin_amdgcn_s_setprio(1);
#pragma unroll
      for (int nd = 0; nd < 4; nd++)
        oacc[nd] = __builtin_amdgcn_mfma_f32_16x16x32_bf16(vf[nd], pf, oacc[nd], 0, 0, 0);
      __builtin_amdgcn_s_setprio(0);
    }
    __syncthreads();
  }

  {
    const int q = q0 + w * 16 + l16;
    bf16* ob = aout + (size_t)(b * 1024 + q) * 768 + h * 64 + g * 4;
#pragma unroll
    for (int nd = 0; nd < 4; nd++) {
      bf16x4 o4;
      o4[0] = (bf16)oacc[nd][0]; o4[1] = (bf16)oacc[nd][1];
      o4[2] = (bf16)oacc[nd][2]; o4[3] = (bf16)oacc[nd][3];
      *(bf16x4*)(ob + nd * 16) = o4;
    }
  }
}

// ---------------- host ----------------
extern "C" void kernel_launch(void* const* d_in, const int* in_sizes, int n_in,
                              void* d_out, int out_size, void* d_ws, size_t ws_size,
                              hipStream_t stream) {
  (void)in_sizes; (void)n_in; (void)out_size; (void)ws_size;
  const float* x = (const float*)d_in[0];
#define IN(d, i) ((const float*)d_in[1 + (d) * 12 + (i)])
  float* outF = (float*)d_out;
  float* attnp[2] = {outF + 3145728, outF + 3145728 + 50331648};

  // 112 KiB dynamic LDS for the 256x192 GEMM (idempotent, capture-safe)
  const int kLds = 114688;
  hipFuncSetAttribute((const void*)gemm256_k<0, 3>,
                      hipFuncAttributeMaxDynamicSharedMemorySize, kLds);
  hipFuncSetAttribute((const void*)gemm256_k<1, 3>,
                      hipFuncAttributeMaxDynamicSharedMemorySize, kLds);
  hipFuncSetAttribute((const void*)gemm256_k<4, 3>,
                      hipFuncAttributeMaxDynamicSharedMemorySize, kLds);

  char* p = (char*)d_ws;
  auto alloc = [&](size_t bytes) { void* r = p; p += bytes; return r; };
  bf16 *qkv_wt[2], *proj_wt[2], *w1t[2], *w2t[2];
  for (int d = 0; d < 2; d++) {
    qkv_wt[d]  = (bf16*)alloc((size_t)2304 * 768 * 2);
    proj_wt[d] = (bf16*)alloc((size_t)768 * 768 * 2);
    w1t[d]     = (bf16*)alloc((size_t)3072 * 768 * 2);
    w2t[d]     = (bf16*)alloc((size_t)768 * 3072 * 2);
  }
  // hbuf+qkvb form one contiguous 25.17 MB region; reused as up to 4 bf16
  // split-K partials (4 x 3145728 elems) while both buffers are dead.
  bf16*  hbuf = (bf16*)alloc((size_t)4096 * 768 * 2);
  bf16*  qkvb = (bf16*)alloc((size_t)4096 * 2304 * 2);
  bf16*  pbuf = hbuf;
  bf16*  vT   = (bf16*)alloc((size_t)48 * 64 * 1024 * 2);
  bf16*  aout = (bf16*)alloc((size_t)4096 * 768 * 2);
  bf16*  hid  = (bf16*)alloc((size_t)4096 * 3072 * 2);
  float* xa   = (float*)alloc((size_t)4096 * 768 * 4);
  float* xb   = (float*)alloc((size_t)4096 * 768 * 4);

  transpose_all_k<<<14848, 256, 0, stream>>>(
      IN(0, 0), qkv_wt[0], IN(0, 2), proj_wt[0], IN(0, 8), w1t[0], IN(0, 10), w2t[0],
      IN(1, 0), qkv_wt[1], IN(1, 2), proj_wt[1], IN(1, 8), w1t[1], IN(1, 10), w2t[1],
      x, IN(0, 4), IN(0, 5), hbuf);

  // ---- layer 0 attention: xa = x + attn0(hbuf); also LN1_1(xa) -> hbuf ----
  gemm256_k<0, 3><<<dim3(12, 16), 512, kLds, stream>>>(hbuf, 768, qkv_wt[0], 768, IN(0, 1),
                                                       qkvb, 2304, 768, vT, 0);
  fattn_k<<<768, 256, 0, stream>>>(qkvb, vT, attnp[0], aout);
  gemm256_k<4, 3><<<dim3(4, 16, 4), 512, kLds, stream>>>(aout, 768, proj_wt[0], 768, nullptr,
                                                         pbuf, 768, 192, nullptr, 3145728);
  reduce_ln_k<4, 0, true><<<1024, 256, 0, stream>>>(pbuf, IN(0, 3), x, nullptr,
                                                    xa, IN(1, 4), IN(1, 5), hbuf);
  // ---- layer 1 attention: xb = xa + attn1(hbuf); also LN2_1(xb) -> hbuf ----
  gemm256_k<0, 3><<<dim3(12, 16), 512, kLds, stream>>>(hbuf, 768, qkv_wt[1], 768, IN(1, 1),
                                                       qkvb, 2304, 768, vT, 0);
  fattn_k<<<768, 256, 0, stream>>>(qkvb, vT, attnp[1], aout);
  gemm256_k<4, 3><<<dim3(4, 16, 4), 512, kLds, stream>>>(aout, 768, proj_wt[1], 768, nullptr,
                                                         pbuf, 768, 192, nullptr, 3145728);
  reduce_ln_k<4, 0, true><<<1024, 256, 0, stream>>>(pbuf, IN(1, 3), xa, nullptr,
                                                    xb, IN(1, 6), IN(1, 7), hbuf);
  // ---- layer 1 MLP + blend: xa = 0.5*(xa + xb + mlp1(hbuf)); LN2_0(xa) -> hbuf ----
  gemm256_k<1, 3><<<dim3(16, 16), 512, kLds, stream>>>(hbuf, 768, w1t[1], 768, IN(1, 9),
                                                       hid, 3072, 768, nullptr, 0);
  gemm256_k<4, 3><<<dim3(4, 16, 4), 512, kLds, stream>>>(hid, 3072, w2t[1], 3072, nullptr,
                                                         pbuf, 768, 768, nullptr, 3145728);
  reduce_ln_k<4, 1, true><<<1024, 256, 0, stream>>>(pbuf, IN(1, 11), xb, xa,
                                                    xa, IN(0, 6), IN(0, 7), hbuf);
  // ---- layer 0 MLP: out = xa + mlp0(hbuf) ----
  gemm256_k<1, 3><<<dim3(16, 16), 512, kLds, stream>>>(hbuf, 768, w1t[0], 768, IN(0, 9),
                                                       hid, 3072, 768, nullptr, 0);
  gemm256_k<4, 3><<<dim3(4, 16, 4), 512, kLds, stream>>>(hid, 3072, w2t[0], 3072, nullptr,
                                                         pbuf, 768, 768, nullptr, 3145728);
  reduce_ln_k<4, 0, false><<<1024, 256, 0, stream>>>(pbuf, IN(0, 11), xa, nullptr,
                                                     outF, nullptr, nullptr, nullptr);
#undef IN
}